// Round 4
// baseline (43255.219 us; speedup 1.0000x reference)
//
#include <hip/hip_runtime.h>
#include <hip/hip_cooperative_groups.h>
#include <math.h>

namespace cg = cooperative_groups;

// Problem constants
#define D_MODEL 1024
#define N_WIN   240
#define TOK     256
#define NH      16
#define DH      64
#define CHUNK   8
#define NCHUNK  30
#define WIN     ((size_t)TOK * D_MODEL)

typedef unsigned short ushort_t;
typedef __attribute__((ext_vector_type(8))) short short8;
typedef __attribute__((ext_vector_type(4))) float floatx4;

__device__ __forceinline__ float blo(unsigned u) {
    return __uint_as_float(u << 16);
}
__device__ __forceinline__ float bhi(unsigned u) {
    return __uint_as_float(u & 0xffff0000u);
}
__device__ __forceinline__ ushort_t f2bf(float f) {   // RNE
    unsigned u = __float_as_uint(f);
    unsigned lsb = (u >> 16) & 1u;
    u += 0x7fffu + lsb;
    return (ushort_t)(u >> 16);
}

// async global->LDS, 16B per lane; LDS dest is wave-uniform base + lane*16
#define GLDS(g, l) __builtin_amdgcn_global_load_lds( \
    (const __attribute__((address_space(1))) unsigned int*)(g), \
    (__attribute__((address_space(3))) unsigned int*)(l), 16, 0, 0)

// ---------------------------------------------------------------------------
// fp32 -> bf16 cast
// ---------------------------------------------------------------------------
__global__ __launch_bounds__(256) void cast_bf_k(
    const float* __restrict__ s, ushort_t* __restrict__ d, int n)
{
    int i = (blockIdx.x * 256 + threadIdx.x) * 4;
    if (i >= n) return;
    float4 v = *(const float4*)(s + i);
    ushort4 o;
    o.x = f2bf(v.x); o.y = f2bf(v.y); o.z = f2bf(v.z); o.w = f2bf(v.w);
    *(ushort4*)(d + i) = o;
}

// ---------------------------------------------------------------------------
// Phase-1 bf16 MFMA GEMM core (m97 structure), 128x128 tile, BK=32.
// ---------------------------------------------------------------------------
template<bool GATHER>
__device__ __forceinline__ void gemm_core(
    const ushort_t* __restrict__ A, int lda, int w0,
    const ushort_t* __restrict__ W, const float* __restrict__ bias,
    ushort_t* __restrict__ Cb, float* __restrict__ Cf, int ldc,
    int K, int m0, int n0, int co, int relu)
{
    __shared__ ushort_t As[128 * 32];
    __shared__ ushort_t Bs[128 * 32];
    const int tid = threadIdx.x;
    const int wave = tid >> 6, lane = tid & 63;
    const int wm = wave & 1, wn = wave >> 1;

    int r0 = m0 + (tid >> 2), r1 = r0 + 64;
    if (GATHER) {
        r0 = (w0 + (r0 >> 8)) * 16 + (r0 & 255);
        r1 = (w0 + (r1 >> 8)) * 16 + (r1 & 255);
    }
    const int kcol = (tid & 3) * 8;
    const ushort_t* gA0 = A + (size_t)r0 * lda + kcol;
    const ushort_t* gA1 = A + (size_t)r1 * lda + kcol;
    const ushort_t* pW  = W + (size_t)n0 * K;
    const ushort_t* gB0 = pW + (size_t)(tid >> 2) * K + kcol;
    const ushort_t* gB1 = gB0 + (size_t)64 * K;
    ushort_t* lA = As + wave * 512;
    ushort_t* lB = Bs + wave * 512;

    floatx4 acc[4][4];
#pragma unroll
    for (int i = 0; i < 4; ++i)
#pragma unroll
        for (int j = 0; j < 4; ++j) acc[i][j] = (floatx4){0.f, 0.f, 0.f, 0.f};

    const int fr = lane & 15, fk = (lane >> 4) * 8;
    const int arow = (wm * 64 + fr) * 32 + fk;
    const int brow = (wn * 64 + fr) * 32 + fk;

    for (int k0 = 0; k0 < K; k0 += 32) {
        GLDS(gA0 + k0, lA);
        GLDS(gA1 + k0, lA + 2048);
        GLDS(gB0 + k0, lB);
        GLDS(gB1 + k0, lB + 2048);
        __syncthreads();
        short8 a[4], b[4];
#pragma unroll
        for (int mi = 0; mi < 4; ++mi) a[mi] = *(const short8*)&As[arow + mi * 512];
#pragma unroll
        for (int ni = 0; ni < 4; ++ni) b[ni] = *(const short8*)&Bs[brow + ni * 512];
#pragma unroll
        for (int mi = 0; mi < 4; ++mi)
#pragma unroll
            for (int ni = 0; ni < 4; ++ni)
                acc[mi][ni] = __builtin_amdgcn_mfma_f32_16x16x32_bf16(
                    a[mi], b[ni], acc[mi][ni], 0, 0, 0);
        __syncthreads();
    }

    const int crq = (lane >> 4) * 4;
    const int ccol = lane & 15;
#pragma unroll
    for (int mi = 0; mi < 4; ++mi) {
#pragma unroll
        for (int ni = 0; ni < 4; ++ni) {
            int lc = wn * 64 + ni * 16 + ccol;
            float bz = bias[n0 + lc];
#pragma unroll
            for (int rg = 0; rg < 4; ++rg) {
                int row = m0 + wm * 64 + mi * 16 + crq + rg;
                float v = acc[mi][ni][rg] + bz;
                if (relu) v = fmaxf(v, 0.f);
                size_t off = (size_t)row * ldc + co + lc;
                if (Cb) Cb[off] = f2bf(v);
                if (Cf) Cf[off] = v;
            }
        }
    }
}

__global__ __launch_bounds__(256) void gemm_bf_k(
    const ushort_t* __restrict__ A, int lda,
    const ushort_t* __restrict__ W, const float* __restrict__ bias,
    ushort_t* __restrict__ Cb, float* __restrict__ Cf, int ldc,
    int K, int relu)
{
    gemm_core<false>(A, lda, 0, W, bias, Cb, Cf, ldc, K,
                     blockIdx.y * 128, blockIdx.x * 128, blockIdx.x * 128, relu);
}

__global__ __launch_bounds__(256) void gemm_qkv_k(
    const ushort_t* __restrict__ path_bf, const ushort_t* __restrict__ W,
    const float* __restrict__ bias, ushort_t* __restrict__ Cb, int w0)
{
    gemm_core<true>(path_bf, 1024, w0, W, bias, Cb, nullptr, 3072, 1024,
                    blockIdx.y * 128, blockIdx.x * 128, blockIdx.x * 128, 0);
}

// ---------------------------------------------------------------------------
// Phase-1 MHA (unchanged from round 3): bf16 in/out, fp32 math.
// ---------------------------------------------------------------------------
__global__ __launch_bounds__(256) void attn_k(
    const ushort_t* __restrict__ Q, const ushort_t* __restrict__ Kp,
    const ushort_t* __restrict__ Vp, ushort_t* __restrict__ O,
    int ldq, int ldk, int ldo,
    long long qBatch, long long kBatch, long long oBatch, float scale)
{
    const int h = blockIdx.y;
    const long long b = blockIdx.z;
    const ushort_t* qb = Q  + b * qBatch + h * DH;
    const ushort_t* kb = Kp + b * kBatch + h * DH;
    const ushort_t* vb = Vp + b * kBatch + h * DH;
    const int tid = threadIdx.x;
    const int rr = tid & 63;
    const int s  = tid >> 6;
    const int r  = (blockIdx.x << 6) + rr;

    float qr[64];
    {
        const uint4* qrow = (const uint4*)(qb + (size_t)r * ldq);
#pragma unroll
        for (int c = 0; c < 8; ++c) {
            uint4 p = qrow[c];
            qr[c * 8 + 0] = blo(p.x); qr[c * 8 + 1] = bhi(p.x);
            qr[c * 8 + 2] = blo(p.y); qr[c * 8 + 3] = bhi(p.y);
            qr[c * 8 + 4] = blo(p.z); qr[c * 8 + 5] = bhi(p.z);
            qr[c * 8 + 6] = blo(p.w); qr[c * 8 + 7] = bhi(p.w);
        }
    }

    float m = -INFINITY, l = 0.f;
    float o[64];
#pragma unroll
    for (int i = 0; i < 64; ++i) o[i] = 0.f;

    const int j0 = s << 6;
    for (int j = j0; j < j0 + 64; ++j) {
        const uint4* krow = (const uint4*)(kb + (size_t)j * ldk);
        float dot = 0.f;
#pragma unroll
        for (int c = 0; c < 8; ++c) {
            uint4 p = krow[c];
            dot = fmaf(qr[c * 8 + 0], blo(p.x), dot);
            dot = fmaf(qr[c * 8 + 1], bhi(p.x), dot);
            dot = fmaf(qr[c * 8 + 2], blo(p.y), dot);
            dot = fmaf(qr[c * 8 + 3], bhi(p.y), dot);
            dot = fmaf(qr[c * 8 + 4], blo(p.z), dot);
            dot = fmaf(qr[c * 8 + 5], bhi(p.z), dot);
            dot = fmaf(qr[c * 8 + 6], blo(p.w), dot);
            dot = fmaf(qr[c * 8 + 7], bhi(p.w), dot);
        }
        float sc = dot * scale;
        float mn = fmaxf(m, sc);
        float alpha = __expf(m - mn);
        float p = __expf(sc - mn);
        l = l * alpha + p;
        m = mn;
        const uint4* vrow = (const uint4*)(vb + (size_t)j * ldk);
#pragma unroll
        for (int c = 0; c < 8; ++c) {
            uint4 pv = vrow[c];
            o[c * 8 + 0] = fmaf(p, blo(pv.x), o[c * 8 + 0] * alpha);
            o[c * 8 + 1] = fmaf(p, bhi(pv.x), o[c * 8 + 1] * alpha);
            o[c * 8 + 2] = fmaf(p, blo(pv.y), o[c * 8 + 2] * alpha);
            o[c * 8 + 3] = fmaf(p, bhi(pv.y), o[c * 8 + 3] * alpha);
            o[c * 8 + 4] = fmaf(p, blo(pv.z), o[c * 8 + 4] * alpha);
            o[c * 8 + 5] = fmaf(p, bhi(pv.z), o[c * 8 + 5] * alpha);
            o[c * 8 + 6] = fmaf(p, blo(pv.w), o[c * 8 + 6] * alpha);
            o[c * 8 + 7] = fmaf(p, bhi(pv.w), o[c * 8 + 7] * alpha);
        }
    }

    __shared__ float sm[4][64];
    __shared__ float sl[4][64];
    __shared__ float Oa[64][68];
    sm[s][rr] = m;
    sl[s][rr] = l;
    __syncthreads();
    float M2 = fmaxf(fmaxf(sm[0][rr], sm[1][rr]), fmaxf(sm[2][rr], sm[3][rr]));
    float L = 0.f;
#pragma unroll
    for (int s2 = 0; s2 < 4; ++s2) L += sl[s2][rr] * __expf(sm[s2][rr] - M2);
    float myw = __expf(m - M2);
#pragma unroll
    for (int i = 0; i < 64; ++i) o[i] *= myw;
#pragma unroll
    for (int p = 0; p < 4; ++p) {
        if (s == p) {
            if (p == 0) {
#pragma unroll
                for (int i = 0; i < 64; ++i) Oa[rr][i] = o[i];
            } else {
#pragma unroll
                for (int i = 0; i < 64; ++i) Oa[rr][i] += o[i];
            }
        }
        __syncthreads();
    }
    float invL = 1.f / L;
    ushort_t* orow = O + b * oBatch + h * DH + (size_t)r * ldo;
#pragma unroll
    for (int i = 0; i < 4; ++i) {
        int d = (s << 4) + (i << 2);
        ushort4 res;
        res.x = f2bf(Oa[rr][d + 0] * invL);
        res.y = f2bf(Oa[rr][d + 1] * invL);
        res.z = f2bf(Oa[rr][d + 2] * invL);
        res.w = f2bf(Oa[rr][d + 3] * invL);
        *(ushort4*)(orow + d) = res;
    }
}

// ===========================================================================
// Cooperative phase-2 kernel: 8 scan steps per launch, 3 grid.sync()/step.
// Grid = 256 WGs x 256 thr (1 WG/CU, co-resident).
// ===========================================================================
#define PLD 260   // P LDS leading dim (bf16 elems), pad to de-conflict b128
#define VLD 132   // V^T half leading dim (128 keys + 4 pad)

struct ScanShared {
    ushort_t P[64 * PLD];    // softmax probs, bf16 row-major [row][key]
    ushort_t VT[64 * VLD];   // V^T half [dim][key-in-half]
    float    l[64];          // row sums
};

// tall-skinny GEMM: C[256 x 16] = A[256 x 1024] @ Wn[16 x 1024]^T + bias_n
// wave v handles rows [v*64, v*64+64) = 4 m-tiles of 16x16x32 MFMA.
__device__ __forceinline__ void ts_gemm(
    const ushort_t* __restrict__ A, const ushort_t* __restrict__ Wn,
    const float* __restrict__ bias_n,
    ushort_t* __restrict__ Cb, float* __restrict__ Cf, int ldc, int cc,
    int wave, int lane)
{
    const int m0v = wave * 64;
    const int fr = lane & 15, fk = (lane >> 4) * 8;
    floatx4 acc[4];
#pragma unroll
    for (int i = 0; i < 4; ++i) acc[i] = (floatx4){0.f, 0.f, 0.f, 0.f};

    const ushort_t* bptr = Wn + (size_t)fr * 1024 + fk;
    const ushort_t* aptr = A + (size_t)(m0v + fr) * 1024 + fk;
    for (int k0 = 0; k0 < 1024; k0 += 32) {
        short8 b = *(const short8*)(bptr + k0);
#pragma unroll
        for (int mi = 0; mi < 4; ++mi) {
            short8 a = *(const short8*)(aptr + (size_t)(mi * 16) * 1024 + k0);
            acc[mi] = __builtin_amdgcn_mfma_f32_16x16x32_bf16(a, b, acc[mi], 0, 0, 0);
        }
    }
    const int q = lane >> 4;
    float bz = bias_n[fr];
#pragma unroll
    for (int mi = 0; mi < 4; ++mi) {
#pragma unroll
        for (int rg = 0; rg < 4; ++rg) {
            int row = m0v + mi * 16 + q * 4 + rg;
            float v = acc[mi][rg] + bz;
            size_t off = (size_t)row * ldc + cc + fr;
            Cb[off] = f2bf(v);
            if (Cf) Cf[off] = v;
        }
    }
}

// MFMA flash attention for one (head, 64-row slice).
__device__ __forceinline__ void coop_attn(
    int w, int tid, const ushort_t* __restrict__ Qb,
    const ushort_t* __restrict__ KVb, ushort_t* __restrict__ AO2,
    ScanShared& sh)
{
    const int h = w >> 2, rs = w & 3;
    const int wave = tid >> 6, lane = tid & 63;
    const int fr = lane & 15, q = lane >> 4, fk = q * 8;
    const ushort_t* Qh = Qb + (size_t)(rs * 64) * 1024 + h * 64;
    const ushort_t* Kh = KVb + h * 64;
    const ushort_t* Vh = KVb + 1024 + h * 64;
    const int m0 = wave * 16;   // wave's 16 rows within the 64-slice

    // ---- S = Q @ K^T (fp32 acc, C-layout regs) ----
    floatx4 s[16];
#pragma unroll
    for (int nt = 0; nt < 16; ++nt) s[nt] = (floatx4){0.f, 0.f, 0.f, 0.f};
#pragma unroll
    for (int kc = 0; kc < 64; kc += 32) {
        short8 a = *(const short8*)(Qh + (size_t)(m0 + fr) * 1024 + kc + fk);
#pragma unroll
        for (int nt = 0; nt < 16; ++nt) {
            short8 b = *(const short8*)(Kh + (size_t)(nt * 16 + fr) * 2048 + kc + fk);
            s[nt] = __builtin_amdgcn_mfma_f32_16x16x32_bf16(a, b, s[nt], 0, 0, 0);
        }
    }

    // ---- softmax over 256 cols; row r = m0 + q*4 + rg, cols on 16 lanes ----
    float rmax[4] = {-INFINITY, -INFINITY, -INFINITY, -INFINITY};
#pragma unroll
    for (int nt = 0; nt < 16; ++nt)
#pragma unroll
        for (int rg = 0; rg < 4; ++rg) rmax[rg] = fmaxf(rmax[rg], s[nt][rg]);
#pragma unroll
    for (int d = 1; d < 16; d <<= 1)
#pragma unroll
        for (int rg = 0; rg < 4; ++rg)
            rmax[rg] = fmaxf(rmax[rg], __shfl_xor(rmax[rg], d));

    float rsum[4] = {0.f, 0.f, 0.f, 0.f};
#pragma unroll
    for (int nt = 0; nt < 16; ++nt) {
#pragma unroll
        for (int rg = 0; rg < 4; ++rg) {
            float p = __expf((s[nt][rg] - rmax[rg]) * 0.125f);
            rsum[rg] += p;
            sh.P[(m0 + q * 4 + rg) * PLD + nt * 16 + fr] = f2bf(p);
        }
    }
#pragma unroll
    for (int d = 1; d < 16; d <<= 1)
#pragma unroll
        for (int rg = 0; rg < 4; ++rg) rsum[rg] += __shfl_xor(rsum[rg], d);
    if (fr == 0) {
#pragma unroll
        for (int rg = 0; rg < 4; ++rg) sh.l[m0 + q * 4 + rg] = rsum[rg];
    }
    __syncthreads();

    // ---- PV: O[64x64] = P[64x256] @ V[256x64], V^T staged in halves ----
    floatx4 o[4];
#pragma unroll
    for (int i = 0; i < 4; ++i) o[i] = (floatx4){0.f, 0.f, 0.f, 0.f};

#pragma unroll
    for (int half = 0; half < 2; ++half) {
        {   // stage V^T for keys [half*128, half*128+128)
            int r = tid & 127, cp = tid >> 7;
            const ushort_t* vrow = Vh + (size_t)(half * 128 + r) * 2048 + cp * 32;
#pragma unroll
            for (int c = 0; c < 4; ++c) {
                uint4 pk = *(const uint4*)(vrow + c * 8);
                int d0 = cp * 32 + c * 8;
                sh.VT[(d0 + 0) * VLD + r] = (ushort_t)(pk.x & 0xffff);
                sh.VT[(d0 + 1) * VLD + r] = (ushort_t)(pk.x >> 16);
                sh.VT[(d0 + 2) * VLD + r] = (ushort_t)(pk.y & 0xffff);
                sh.VT[(d0 + 3) * VLD + r] = (ushort_t)(pk.y >> 16);
                sh.VT[(d0 + 4) * VLD + r] = (ushort_t)(pk.z & 0xffff);
                sh.VT[(d0 + 5) * VLD + r] = (ushort_t)(pk.z >> 16);
                sh.VT[(d0 + 6) * VLD + r] = (ushort_t)(pk.w & 0xffff);
                sh.VT[(d0 + 7) * VLD + r] = (ushort_t)(pk.w >> 16);
            }
        }
        __syncthreads();
#pragma unroll
        for (int ks = 0; ks < 4; ++ks) {
            short8 a = *(const short8*)&sh.P[(m0 + fr) * PLD + half * 128 + ks * 32 + fk];
#pragma unroll
            for (int nt2 = 0; nt2 < 4; ++nt2) {
                short8 b = *(const short8*)&sh.VT[(nt2 * 16 + fr) * VLD + ks * 32 + fk];
                o[nt2] = __builtin_amdgcn_mfma_f32_16x16x32_bf16(a, b, o[nt2], 0, 0, 0);
            }
        }
        __syncthreads();   // protect VT before next half's staging
    }

    // ---- epilogue: divide by l, write AO2 (bf16) ----
    float linv[4];
#pragma unroll
    for (int rg = 0; rg < 4; ++rg) linv[rg] = 1.f / sh.l[m0 + q * 4 + rg];
#pragma unroll
    for (int nt2 = 0; nt2 < 4; ++nt2)
#pragma unroll
        for (int rg = 0; rg < 4; ++rg) {
            int row = rs * 64 + m0 + q * 4 + rg;
            AO2[(size_t)row * 1024 + h * 64 + nt2 * 16 + fr] =
                f2bf(o[nt2][rg] * linv[rg]);
        }
}

__global__ __launch_bounds__(256, 1) void scan_coop_k(
    const ushort_t* __restrict__ Xchunk, int w0, int i0, int nsteps,
    ushort_t* __restrict__ cum,
    ushort_t* __restrict__ Qb, ushort_t* __restrict__ KVb,
    ushort_t* __restrict__ AO2,
    const ushort_t* __restrict__ w_in2, const float* __restrict__ b_in2,
    const ushort_t* __restrict__ w_out2, const float* __restrict__ b_out2,
    float* __restrict__ outp)
{
    __shared__ ScanShared sh;
    cg::grid_group grid = cg::this_grid();
    const int wg = blockIdx.x, tid = threadIdx.x;
    const int wave = tid >> 6, lane = tid & 63;

    for (int t = 0; t < nsteps; ++t) {
        const int i = i0 + t;
        const ushort_t* Xi = Xchunk + (size_t)(i - w0) * WIN;

        // Stage A: QKV projection (192 WGs x 16 cols)
        if (wg < 192) {
            const int n0 = wg * 16;
            const ushort_t* A = (n0 < 1024) ? Xi : cum;
            ushort_t* Cb; int ldc, cc;
            if (n0 < 1024) { Cb = Qb;  ldc = 1024; cc = n0; }
            else           { Cb = KVb; ldc = 2048; cc = n0 - 1024; }
            ts_gemm(A, w_in2 + (size_t)n0 * 1024, b_in2 + n0,
                    Cb, nullptr, ldc, cc, wave, lane);
        }
        grid.sync();

        // Stage B: MFMA flash attention (64 WGs = 16 heads x 4 row-slices)
        if (wg < 64) coop_attn(wg, tid, Qb, KVb, AO2, sh);
        grid.sync();

        // Stage C: out projection (64 WGs x 16 cols) -> cum (+ fp32 out)
        if (wg < 64) {
            const int n0 = wg * 16;
            float* Cf = (i == N_WIN - 1) ? outp : nullptr;
            ts_gemm(AO2, w_out2 + (size_t)n0 * 1024, b_out2 + n0,
                    cum, Cf, 1024, n0, wave, lane);
        }
        grid.sync();
    }
}

// ---------------------------------------------------------------------------
extern "C" void kernel_launch(void* const* d_in, const int* in_sizes, int n_in,
                              void* d_out, int out_size, void* d_ws, size_t ws_size,
                              hipStream_t stream)
{
    const float* path   = (const float*)d_in[0];
    const float* w_in1  = (const float*)d_in[1];
    const float* b_in1  = (const float*)d_in[2];
    const float* w_out1 = (const float*)d_in[3];
    const float* b_out1 = (const float*)d_in[4];
    const float* w_lin  = (const float*)d_in[5];
    const float* b_lin  = (const float*)d_in[6];
    const float* w_in2  = (const float*)d_in[7];
    const float* b_in2  = (const float*)d_in[8];
    const float* w_out2 = (const float*)d_in[9];
    const float* b_out2 = (const float*)d_in[10];
    float* out = (float*)d_out;

    // workspace (bf16 elems) — ~53 MB
    ushort_t* ws = (ushort_t*)d_ws;
    ushort_t* path_bf  = ws;                              // 4096*1024
    ushort_t* w_in1_bf = path_bf  + (size_t)4096 * 1024;  // 3072*1024
    ushort_t* w_out1_bf= w_in1_bf + (size_t)3072 * 1024;
    ushort_t* w_lin_bf = w_out1_bf+ (size_t)1024 * 1024;
    ushort_t* w_in2_bf = w_lin_bf + (size_t)1024 * 1024;  // 3072*1024
    ushort_t* w_out2_bf= w_in2_bf + (size_t)3072 * 1024;
    ushort_t* qkv_bf   = w_out2_bf+ (size_t)1024 * 1024;  // 2048*3072
    ushort_t* ao_bf    = qkv_bf   + (size_t)2048 * 3072;
    ushort_t* ybuf_bf  = ao_bf    + (size_t)2048 * 1024;
    ushort_t* Xchunk   = ybuf_bf  + (size_t)2048 * 1024;  // 2048*1024
    ushort_t* Qb       = Xchunk   + (size_t)2048 * 1024;
    ushort_t* KVb      = Qb  + WIN;                       // 256*2048
    ushort_t* AO2      = KVb + 2 * WIN;
    ushort_t* cum      = AO2 + WIN;

    const float scale = 0.125f;
    const int Mc = CHUNK * TOK;   // 2048

    cast_bf_k<<<4096, 256, 0, stream>>>(path,  path_bf,  4096 * 1024);
    cast_bf_k<<<3072, 256, 0, stream>>>(w_in1, w_in1_bf, 3072 * 1024);
    cast_bf_k<<<1024, 256, 0, stream>>>(w_out1, w_out1_bf, 1024 * 1024);
    cast_bf_k<<<1024, 256, 0, stream>>>(w_lin, w_lin_bf, 1024 * 1024);
    cast_bf_k<<<3072, 256, 0, stream>>>(w_in2, w_in2_bf, 3072 * 1024);
    cast_bf_k<<<1024, 256, 0, stream>>>(w_out2, w_out2_bf, 1024 * 1024);

    for (int c = 0; c < NCHUNK; ++c) {
        int w0 = c * CHUNK;
        // ---- Phase 1 for windows [w0, w0+CHUNK) ----
        gemm_qkv_k<<<dim3(24, 16), 256, 0, stream>>>(
            path_bf, w_in1_bf, b_in1, qkv_bf, w0);
        attn_k<<<dim3(4, NH, CHUNK), 256, 0, stream>>>(
            qkv_bf, qkv_bf + 1024, qkv_bf + 2048, ao_bf,
            3072, 3072, 1024,
            (long long)TOK * 3072, (long long)TOK * 3072,
            (long long)TOK * 1024, scale);
        gemm_bf_k<<<dim3(8, 16), 256, 0, stream>>>(
            ao_bf, 1024, w_out1_bf, b_out1, ybuf_bf, nullptr, 1024, 1024, 0);
        gemm_bf_k<<<dim3(8, 16), 256, 0, stream>>>(
            ybuf_bf, 1024, w_lin_bf, b_lin, Xchunk, nullptr, 1024, 1024, 1);

        // ---- Phase 2: one cooperative launch for this chunk's scan steps ----
        if (c == 0) {
            // cum_0 = x[0]
            hipMemcpyAsync(cum, Xchunk, WIN * sizeof(ushort_t),
                           hipMemcpyDeviceToDevice, stream);
        }
        int i0 = (c == 0) ? 1 : w0;
        int nsteps = (c == 0) ? CHUNK - 1 : CHUNK;
        const ushort_t* XchunkP = Xchunk;
        ushort_t *cumP = cum, *QbP = Qb, *KVbP = KVb, *AO2P = AO2;
        const ushort_t *win2P = w_in2_bf, *wout2P = w_out2_bf;
        const float *bin2P = b_in2, *bout2P = b_out2;
        float* outP = out;
        int w0v = w0;
        void* args[] = {&XchunkP, &w0v, &i0, &nsteps, &cumP, &QbP, &KVbP,
                        &AO2P, &win2P, &bin2P, &wout2P, &bout2P, &outP};
        hipLaunchCooperativeKernel((void*)scan_coop_k, dim3(256), dim3(256),
                                   args, 0, stream);
    }
}

// Round 5
// 41083.191 us; speedup vs baseline: 1.0529x; 1.0529x over previous
//
#include <hip/hip_runtime.h>
#include <math.h>

// Problem constants
#define D_MODEL 1024
#define N_WIN   240
#define TOK     256
#define NH      16
#define DH      64
#define CHUNK   8
#define NCHUNK  30
#define WIN     ((size_t)TOK * D_MODEL)
#define NWG     256

typedef unsigned short ushort_t;
typedef __attribute__((ext_vector_type(8))) short short8;
typedef __attribute__((ext_vector_type(4))) float floatx4;

__device__ __forceinline__ float blo(unsigned u) {
    return __uint_as_float(u << 16);
}
__device__ __forceinline__ float bhi(unsigned u) {
    return __uint_as_float(u & 0xffff0000u);
}
__device__ __forceinline__ ushort_t f2bf(float f) {   // RNE
    unsigned u = __float_as_uint(f);
    unsigned lsb = (u >> 16) & 1u;
    u += 0x7fffu + lsb;
    return (ushort_t)(u >> 16);
}

// async global->LDS, 16B per lane; LDS dest is wave-uniform base + lane*16
#define GLDS(g, l) __builtin_amdgcn_global_load_lds( \
    (const __attribute__((address_space(1))) unsigned int*)(g), \
    (__attribute__((address_space(3))) unsigned int*)(l), 16, 0, 0)

// ---------------------------------------------------------------------------
// Hand-rolled grid barrier: monotonic epoch counter, device scope.
// Arrival: release-fence + relaxed atomicAdd. Spin: relaxed agent-scope load
// (fresh value via scope-driven cache bits, no per-poll L2 invalidate) with
// s_sleep backoff; one acquire fence after the target is observed.
// ---------------------------------------------------------------------------
__device__ __forceinline__ void gbar(unsigned* cnt, unsigned target)
{
    __syncthreads();
    if (threadIdx.x == 0) {
        __threadfence();   // release: make this WG's writes device-visible
        __hip_atomic_fetch_add(cnt, 1u, __ATOMIC_RELAXED,
                               __HIP_MEMORY_SCOPE_AGENT);
        while (__hip_atomic_load(cnt, __ATOMIC_RELAXED,
                                 __HIP_MEMORY_SCOPE_AGENT) < target) {
            __builtin_amdgcn_s_sleep(2);
        }
        __threadfence();   // acquire: invalidate stale lines before reads
    }
    __syncthreads();
}

// ---------------------------------------------------------------------------
// fp32 -> bf16 cast
// ---------------------------------------------------------------------------
__global__ __launch_bounds__(256) void cast_bf_k(
    const float* __restrict__ s, ushort_t* __restrict__ d, int n)
{
    int i = (blockIdx.x * 256 + threadIdx.x) * 4;
    if (i >= n) return;
    float4 v = *(const float4*)(s + i);
    ushort4 o;
    o.x = f2bf(v.x); o.y = f2bf(v.y); o.z = f2bf(v.z); o.w = f2bf(v.w);
    *(ushort4*)(d + i) = o;
}

// ---------------------------------------------------------------------------
// Phase-1 bf16 MFMA GEMM core (m97 structure), 128x128 tile, BK=32.
// ---------------------------------------------------------------------------
template<bool GATHER>
__device__ __forceinline__ void gemm_core(
    const ushort_t* __restrict__ A, int lda, int w0,
    const ushort_t* __restrict__ W, const float* __restrict__ bias,
    ushort_t* __restrict__ Cb, float* __restrict__ Cf, int ldc,
    int K, int m0, int n0, int co, int relu)
{
    __shared__ ushort_t As[128 * 32];
    __shared__ ushort_t Bs[128 * 32];
    const int tid = threadIdx.x;
    const int wave = tid >> 6, lane = tid & 63;
    const int wm = wave & 1, wn = wave >> 1;

    int r0 = m0 + (tid >> 2), r1 = r0 + 64;
    if (GATHER) {
        r0 = (w0 + (r0 >> 8)) * 16 + (r0 & 255);
        r1 = (w0 + (r1 >> 8)) * 16 + (r1 & 255);
    }
    const int kcol = (tid & 3) * 8;
    const ushort_t* gA0 = A + (size_t)r0 * lda + kcol;
    const ushort_t* gA1 = A + (size_t)r1 * lda + kcol;
    const ushort_t* pW  = W + (size_t)n0 * K;
    const ushort_t* gB0 = pW + (size_t)(tid >> 2) * K + kcol;
    const ushort_t* gB1 = gB0 + (size_t)64 * K;
    ushort_t* lA = As + wave * 512;
    ushort_t* lB = Bs + wave * 512;

    floatx4 acc[4][4];
#pragma unroll
    for (int i = 0; i < 4; ++i)
#pragma unroll
        for (int j = 0; j < 4; ++j) acc[i][j] = (floatx4){0.f, 0.f, 0.f, 0.f};

    const int fr = lane & 15, fk = (lane >> 4) * 8;
    const int arow = (wm * 64 + fr) * 32 + fk;
    const int brow = (wn * 64 + fr) * 32 + fk;

    for (int k0 = 0; k0 < K; k0 += 32) {
        GLDS(gA0 + k0, lA);
        GLDS(gA1 + k0, lA + 2048);
        GLDS(gB0 + k0, lB);
        GLDS(gB1 + k0, lB + 2048);
        __syncthreads();
        short8 a[4], b[4];
#pragma unroll
        for (int mi = 0; mi < 4; ++mi) a[mi] = *(const short8*)&As[arow + mi * 512];
#pragma unroll
        for (int ni = 0; ni < 4; ++ni) b[ni] = *(const short8*)&Bs[brow + ni * 512];
#pragma unroll
        for (int mi = 0; mi < 4; ++mi)
#pragma unroll
            for (int ni = 0; ni < 4; ++ni)
                acc[mi][ni] = __builtin_amdgcn_mfma_f32_16x16x32_bf16(
                    a[mi], b[ni], acc[mi][ni], 0, 0, 0);
        __syncthreads();
    }

    const int crq = (lane >> 4) * 4;
    const int ccol = lane & 15;
#pragma unroll
    for (int mi = 0; mi < 4; ++mi) {
#pragma unroll
        for (int ni = 0; ni < 4; ++ni) {
            int lc = wn * 64 + ni * 16 + ccol;
            float bz = bias[n0 + lc];
#pragma unroll
            for (int rg = 0; rg < 4; ++rg) {
                int row = m0 + wm * 64 + mi * 16 + crq + rg;
                float v = acc[mi][ni][rg] + bz;
                if (relu) v = fmaxf(v, 0.f);
                size_t off = (size_t)row * ldc + co + lc;
                if (Cb) Cb[off] = f2bf(v);
                if (Cf) Cf[off] = v;
            }
        }
    }
}

__global__ __launch_bounds__(256) void gemm_bf_k(
    const ushort_t* __restrict__ A, int lda,
    const ushort_t* __restrict__ W, const float* __restrict__ bias,
    ushort_t* __restrict__ Cb, float* __restrict__ Cf, int ldc,
    int K, int relu)
{
    gemm_core<false>(A, lda, 0, W, bias, Cb, Cf, ldc, K,
                     blockIdx.y * 128, blockIdx.x * 128, blockIdx.x * 128, relu);
}

__global__ __launch_bounds__(256) void gemm_qkv_k(
    const ushort_t* __restrict__ path_bf, const ushort_t* __restrict__ W,
    const float* __restrict__ bias, ushort_t* __restrict__ Cb, int w0)
{
    gemm_core<true>(path_bf, 1024, w0, W, bias, Cb, nullptr, 3072, 1024,
                    blockIdx.y * 128, blockIdx.x * 128, blockIdx.x * 128, 0);
}

// ---------------------------------------------------------------------------
// Phase-1 MHA: bf16 in/out, fp32 math, online softmax.
// ---------------------------------------------------------------------------
__global__ __launch_bounds__(256) void attn_k(
    const ushort_t* __restrict__ Q, const ushort_t* __restrict__ Kp,
    const ushort_t* __restrict__ Vp, ushort_t* __restrict__ O,
    int ldq, int ldk, int ldo,
    long long qBatch, long long kBatch, long long oBatch, float scale)
{
    const int h = blockIdx.y;
    const long long b = blockIdx.z;
    const ushort_t* qb = Q  + b * qBatch + h * DH;
    const ushort_t* kb = Kp + b * kBatch + h * DH;
    const ushort_t* vb = Vp + b * kBatch + h * DH;
    const int tid = threadIdx.x;
    const int rr = tid & 63;
    const int s  = tid >> 6;
    const int r  = (blockIdx.x << 6) + rr;

    float qr[64];
    {
        const uint4* qrow = (const uint4*)(qb + (size_t)r * ldq);
#pragma unroll
        for (int c = 0; c < 8; ++c) {
            uint4 p = qrow[c];
            qr[c * 8 + 0] = blo(p.x); qr[c * 8 + 1] = bhi(p.x);
            qr[c * 8 + 2] = blo(p.y); qr[c * 8 + 3] = bhi(p.y);
            qr[c * 8 + 4] = blo(p.z); qr[c * 8 + 5] = bhi(p.z);
            qr[c * 8 + 6] = blo(p.w); qr[c * 8 + 7] = bhi(p.w);
        }
    }

    float m = -INFINITY, l = 0.f;
    float o[64];
#pragma unroll
    for (int i = 0; i < 64; ++i) o[i] = 0.f;

    const int j0 = s << 6;
    for (int j = j0; j < j0 + 64; ++j) {
        const uint4* krow = (const uint4*)(kb + (size_t)j * ldk);
        float dot = 0.f;
#pragma unroll
        for (int c = 0; c < 8; ++c) {
            uint4 p = krow[c];
            dot = fmaf(qr[c * 8 + 0], blo(p.x), dot);
            dot = fmaf(qr[c * 8 + 1], bhi(p.x), dot);
            dot = fmaf(qr[c * 8 + 2], blo(p.y), dot);
            dot = fmaf(qr[c * 8 + 3], bhi(p.y), dot);
            dot = fmaf(qr[c * 8 + 4], blo(p.z), dot);
            dot = fmaf(qr[c * 8 + 5], bhi(p.z), dot);
            dot = fmaf(qr[c * 8 + 6], blo(p.w), dot);
            dot = fmaf(qr[c * 8 + 7], bhi(p.w), dot);
        }
        float sc = dot * scale;
        float mn = fmaxf(m, sc);
        float alpha = __expf(m - mn);
        float p = __expf(sc - mn);
        l = l * alpha + p;
        m = mn;
        const uint4* vrow = (const uint4*)(vb + (size_t)j * ldk);
#pragma unroll
        for (int c = 0; c < 8; ++c) {
            uint4 pv = vrow[c];
            o[c * 8 + 0] = fmaf(p, blo(pv.x), o[c * 8 + 0] * alpha);
            o[c * 8 + 1] = fmaf(p, bhi(pv.x), o[c * 8 + 1] * alpha);
            o[c * 8 + 2] = fmaf(p, blo(pv.y), o[c * 8 + 2] * alpha);
            o[c * 8 + 3] = fmaf(p, bhi(pv.y), o[c * 8 + 3] * alpha);
            o[c * 8 + 4] = fmaf(p, blo(pv.z), o[c * 8 + 4] * alpha);
            o[c * 8 + 5] = fmaf(p, bhi(pv.z), o[c * 8 + 5] * alpha);
            o[c * 8 + 6] = fmaf(p, blo(pv.w), o[c * 8 + 6] * alpha);
            o[c * 8 + 7] = fmaf(p, bhi(pv.w), o[c * 8 + 7] * alpha);
        }
    }

    __shared__ float sm[4][64];
    __shared__ float sl[4][64];
    __shared__ float Oa[64][68];
    sm[s][rr] = m;
    sl[s][rr] = l;
    __syncthreads();
    float M2 = fmaxf(fmaxf(sm[0][rr], sm[1][rr]), fmaxf(sm[2][rr], sm[3][rr]));
    float L = 0.f;
#pragma unroll
    for (int s2 = 0; s2 < 4; ++s2) L += sl[s2][rr] * __expf(sm[s2][rr] - M2);
    float myw = __expf(m - M2);
#pragma unroll
    for (int i = 0; i < 64; ++i) o[i] *= myw;
#pragma unroll
    for (int p = 0; p < 4; ++p) {
        if (s == p) {
            if (p == 0) {
#pragma unroll
                for (int i = 0; i < 64; ++i) Oa[rr][i] = o[i];
            } else {
#pragma unroll
                for (int i = 0; i < 64; ++i) Oa[rr][i] += o[i];
            }
        }
        __syncthreads();
    }
    float invL = 1.f / L;
    ushort_t* orow = O + b * oBatch + h * DH + (size_t)r * ldo;
#pragma unroll
    for (int i = 0; i < 4; ++i) {
        int d = (s << 4) + (i << 2);
        ushort4 res;
        res.x = f2bf(Oa[rr][d + 0] * invL);
        res.y = f2bf(Oa[rr][d + 1] * invL);
        res.z = f2bf(Oa[rr][d + 2] * invL);
        res.w = f2bf(Oa[rr][d + 3] * invL);
        *(ushort4*)(orow + d) = res;
    }
}

// ===========================================================================
// Cooperative phase-2 kernel: 8 scan steps per launch, hand-rolled barriers.
// Grid = 256 WGs x 256 thr. Q is precomputed per chunk in phase 1.
// ===========================================================================
#define PLD 260   // P LDS leading dim (bf16), pad to de-conflict b128
#define VLD 132   // V^T half leading dim (128 keys + 4 pad)

struct ScanShared {
    ushort_t P[64 * PLD];
    ushort_t VT[64 * VLD];
    float    l[64];
};

// tall-skinny GEMM: C[256 x 16] = A[256 x 1024] @ Wn[16 x 1024]^T + bias_n
__device__ __forceinline__ void ts_gemm(
    const ushort_t* __restrict__ A, const ushort_t* __restrict__ Wn,
    const float* __restrict__ bias_n,
    ushort_t* __restrict__ Cb, float* __restrict__ Cf, int ldc, int cc,
    int wave, int lane)
{
    const int m0v = wave * 64;
    const int fr = lane & 15, fk = (lane >> 4) * 8;
    floatx4 acc[4];
#pragma unroll
    for (int i = 0; i < 4; ++i) acc[i] = (floatx4){0.f, 0.f, 0.f, 0.f};

    const ushort_t* bptr = Wn + (size_t)fr * 1024 + fk;
    const ushort_t* aptr = A + (size_t)(m0v + fr) * 1024 + fk;
    for (int k0 = 0; k0 < 1024; k0 += 32) {
        short8 b = *(const short8*)(bptr + k0);
#pragma unroll
        for (int mi = 0; mi < 4; ++mi) {
            short8 a = *(const short8*)(aptr + (size_t)(mi * 16) * 1024 + k0);
            acc[mi] = __builtin_amdgcn_mfma_f32_16x16x32_bf16(a, b, acc[mi], 0, 0, 0);
        }
    }
    const int q = lane >> 4;
    float bz = bias_n[fr];
#pragma unroll
    for (int mi = 0; mi < 4; ++mi) {
#pragma unroll
        for (int rg = 0; rg < 4; ++rg) {
            int row = m0v + mi * 16 + q * 4 + rg;
            float v = acc[mi][rg] + bz;
            size_t off = (size_t)row * ldc + cc + fr;
            Cb[off] = f2bf(v);
            if (Cf) Cf[off] = v;
        }
    }
}

// MFMA flash attention for one (head, 64-row slice). Q from Qstep (ld 1024).
__device__ __forceinline__ void coop_attn(
    int w, int tid, const ushort_t* __restrict__ Qstep,
    const ushort_t* __restrict__ KVb, ushort_t* __restrict__ AO2,
    ScanShared& sh)
{
    const int h = w >> 2, rs = w & 3;
    const int wave = tid >> 6, lane = tid & 63;
    const int fr = lane & 15, q = lane >> 4, fk = q * 8;
    const ushort_t* Qh = Qstep + (size_t)(rs * 64) * 1024 + h * 64;
    const ushort_t* Kh = KVb + h * 64;
    const ushort_t* Vh = KVb + 1024 + h * 64;
    const int m0 = wave * 16;

    floatx4 s[16];
#pragma unroll
    for (int nt = 0; nt < 16; ++nt) s[nt] = (floatx4){0.f, 0.f, 0.f, 0.f};
#pragma unroll
    for (int kc = 0; kc < 64; kc += 32) {
        short8 a = *(const short8*)(Qh + (size_t)(m0 + fr) * 1024 + kc + fk);
#pragma unroll
        for (int nt = 0; nt < 16; ++nt) {
            short8 b = *(const short8*)(Kh + (size_t)(nt * 16 + fr) * 2048 + kc + fk);
            s[nt] = __builtin_amdgcn_mfma_f32_16x16x32_bf16(a, b, s[nt], 0, 0, 0);
        }
    }

    float rmax[4] = {-INFINITY, -INFINITY, -INFINITY, -INFINITY};
#pragma unroll
    for (int nt = 0; nt < 16; ++nt)
#pragma unroll
        for (int rg = 0; rg < 4; ++rg) rmax[rg] = fmaxf(rmax[rg], s[nt][rg]);
#pragma unroll
    for (int d = 1; d < 16; d <<= 1)
#pragma unroll
        for (int rg = 0; rg < 4; ++rg)
            rmax[rg] = fmaxf(rmax[rg], __shfl_xor(rmax[rg], d));

    float rsum[4] = {0.f, 0.f, 0.f, 0.f};
#pragma unroll
    for (int nt = 0; nt < 16; ++nt) {
#pragma unroll
        for (int rg = 0; rg < 4; ++rg) {
            float p = __expf((s[nt][rg] - rmax[rg]) * 0.125f);
            rsum[rg] += p;
            sh.P[(m0 + q * 4 + rg) * PLD + nt * 16 + fr] = f2bf(p);
        }
    }
#pragma unroll
    for (int d = 1; d < 16; d <<= 1)
#pragma unroll
        for (int rg = 0; rg < 4; ++rg) rsum[rg] += __shfl_xor(rsum[rg], d);
    if (fr == 0) {
#pragma unroll
        for (int rg = 0; rg < 4; ++rg) sh.l[m0 + q * 4 + rg] = rsum[rg];
    }
    __syncthreads();

    floatx4 o[4];
#pragma unroll
    for (int i = 0; i < 4; ++i) o[i] = (floatx4){0.f, 0.f, 0.f, 0.f};

#pragma unroll
    for (int half = 0; half < 2; ++half) {
        {
            int r = tid & 127, cp = tid >> 7;
            const ushort_t* vrow = Vh + (size_t)(half * 128 + r) * 2048 + cp * 32;
#pragma unroll
            for (int c = 0; c < 4; ++c) {
                uint4 pk = *(const uint4*)(vrow + c * 8);
                int d0 = cp * 32 + c * 8;
                sh.VT[(d0 + 0) * VLD + r] = (ushort_t)(pk.x & 0xffff);
                sh.VT[(d0 + 1) * VLD + r] = (ushort_t)(pk.x >> 16);
                sh.VT[(d0 + 2) * VLD + r] = (ushort_t)(pk.y & 0xffff);
                sh.VT[(d0 + 3) * VLD + r] = (ushort_t)(pk.y >> 16);
                sh.VT[(d0 + 4) * VLD + r] = (ushort_t)(pk.z & 0xffff);
                sh.VT[(d0 + 5) * VLD + r] = (ushort_t)(pk.z >> 16);
                sh.VT[(d0 + 6) * VLD + r] = (ushort_t)(pk.w & 0xffff);
                sh.VT[(d0 + 7) * VLD + r] = (ushort_t)(pk.w >> 16);
            }
        }
        __syncthreads();
#pragma unroll
        for (int ks = 0; ks < 4; ++ks) {
            short8 a = *(const short8*)&sh.P[(m0 + fr) * PLD + half * 128 + ks * 32 + fk];
#pragma unroll
            for (int nt2 = 0; nt2 < 4; ++nt2) {
                short8 b = *(const short8*)&sh.VT[(nt2 * 16 + fr) * VLD + ks * 32 + fk];
                o[nt2] = __builtin_amdgcn_mfma_f32_16x16x32_bf16(a, b, o[nt2], 0, 0, 0);
            }
        }
        __syncthreads();
    }

    float linv[4];
#pragma unroll
    for (int rg = 0; rg < 4; ++rg) linv[rg] = 1.f / sh.l[m0 + q * 4 + rg];
#pragma unroll
    for (int nt2 = 0; nt2 < 4; ++nt2)
#pragma unroll
        for (int rg = 0; rg < 4; ++rg) {
            int row = rs * 64 + m0 + q * 4 + rg;
            AO2[(size_t)row * 1024 + h * 64 + nt2 * 16 + fr] =
                f2bf(o[nt2][rg] * linv[rg]);
        }
}

__global__ __launch_bounds__(256, 1) void scan_coop_k(
    const ushort_t* __restrict__ Qchunk, int i0, int w0, int nsteps,
    ushort_t* __restrict__ cum, ushort_t* __restrict__ KVb,
    ushort_t* __restrict__ AO2,
    const ushort_t* __restrict__ w_in2, const float* __restrict__ b_in2,
    const ushort_t* __restrict__ w_out2, const float* __restrict__ b_out2,
    float* __restrict__ outp, unsigned* __restrict__ bar, unsigned epoch0)
{
    __shared__ ScanShared sh;
    const int wg = blockIdx.x, tid = threadIdx.x;
    const int wave = tid >> 6, lane = tid & 63;
    unsigned epoch = epoch0;

    for (int t = 0; t < nsteps; ++t) {
        const int i = i0 + t;
        const int il = i - w0;

        // Stage A: KV projection (128 WGs x 16 cols of the 2048 KV cols)
        if (wg < 128) {
            const int n0 = wg * 16;
            ts_gemm(cum, w_in2 + (size_t)(1024 + n0) * 1024,
                    b_in2 + 1024 + n0, KVb, nullptr, 2048, n0, wave, lane);
        }
        ++epoch; gbar(bar, NWG * epoch);

        // Stage B: MFMA flash attention (64 WGs = 16 heads x 4 row-slices)
        if (wg < 64) coop_attn(wg, tid, Qchunk + (size_t)il * WIN, KVb, AO2, sh);
        ++epoch; gbar(bar, NWG * epoch);

        // Stage C: out projection (64 WGs x 16 cols) -> cum (+ fp32 out)
        if (wg < 64) {
            const int n0 = wg * 16;
            float* Cf = (i == N_WIN - 1) ? outp : nullptr;
            ts_gemm(AO2, w_out2 + (size_t)n0 * 1024, b_out2 + n0,
                    cum, Cf, 1024, n0, wave, lane);
        }
        ++epoch; gbar(bar, NWG * epoch);
    }
}

// ---------------------------------------------------------------------------
extern "C" void kernel_launch(void* const* d_in, const int* in_sizes, int n_in,
                              void* d_out, int out_size, void* d_ws, size_t ws_size,
                              hipStream_t stream)
{
    const float* path   = (const float*)d_in[0];
    const float* w_in1  = (const float*)d_in[1];
    const float* b_in1  = (const float*)d_in[2];
    const float* w_out1 = (const float*)d_in[3];
    const float* b_out1 = (const float*)d_in[4];
    const float* w_lin  = (const float*)d_in[5];
    const float* b_lin  = (const float*)d_in[6];
    const float* w_in2  = (const float*)d_in[7];
    const float* b_in2  = (const float*)d_in[8];
    const float* w_out2 = (const float*)d_in[9];
    const float* b_out2 = (const float*)d_in[10];
    float* out = (float*)d_out;

    // workspace layout: barrier (256 B) first, then bf16 buffers (~55 MB)
    unsigned* bar = (unsigned*)d_ws;
    ushort_t* ws = (ushort_t*)d_ws + 128;
    ushort_t* path_bf  = ws;                              // 4096*1024
    ushort_t* w_in1_bf = path_bf  + (size_t)4096 * 1024;  // 3072*1024
    ushort_t* w_out1_bf= w_in1_bf + (size_t)3072 * 1024;
    ushort_t* w_lin_bf = w_out1_bf+ (size_t)1024 * 1024;
    ushort_t* w_in2_bf = w_lin_bf + (size_t)1024 * 1024;  // 3072*1024
    ushort_t* w_out2_bf= w_in2_bf + (size_t)3072 * 1024;
    ushort_t* qkv_bf   = w_out2_bf+ (size_t)1024 * 1024;  // 2048*3072
    ushort_t* ybuf_bf  = qkv_bf;                          // alias: qkv dead by then
    ushort_t* ao_bf    = qkv_bf   + (size_t)2048 * 3072;  // 2048*1024
    ushort_t* Xchunk   = ao_bf    + (size_t)2048 * 1024;  // 2048*1024
    ushort_t* Qchunk   = Xchunk   + (size_t)2048 * 1024;  // 2048*1024
    ushort_t* KVb      = Qchunk   + (size_t)2048 * 1024;  // 256*2048
    ushort_t* AO2      = KVb + 2 * WIN;                   // 256*1024
    ushort_t* cum      = AO2 + WIN;                       // 256*1024

    const float scale = 0.125f;

    hipMemsetAsync(bar, 0, 256, stream);

    cast_bf_k<<<4096, 256, 0, stream>>>(path,  path_bf,  4096 * 1024);
    cast_bf_k<<<3072, 256, 0, stream>>>(w_in1, w_in1_bf, 3072 * 1024);
    cast_bf_k<<<1024, 256, 0, stream>>>(w_out1, w_out1_bf, 1024 * 1024);
    cast_bf_k<<<1024, 256, 0, stream>>>(w_lin, w_lin_bf, 1024 * 1024);
    cast_bf_k<<<3072, 256, 0, stream>>>(w_in2, w_in2_bf, 3072 * 1024);
    cast_bf_k<<<1024, 256, 0, stream>>>(w_out2, w_out2_bf, 1024 * 1024);

    unsigned epoch_base = 0;
    for (int c = 0; c < NCHUNK; ++c) {
        int w0 = c * CHUNK;
        // ---- Phase 1 for windows [w0, w0+CHUNK) ----
        gemm_qkv_k<<<dim3(24, 16), 256, 0, stream>>>(
            path_bf, w_in1_bf, b_in1, qkv_bf, w0);
        attn_k<<<dim3(4, NH, CHUNK), 256, 0, stream>>>(
            qkv_bf, qkv_bf + 1024, qkv_bf + 2048, ao_bf,
            3072, 3072, 1024,
            (long long)TOK * 3072, (long long)TOK * 3072,
            (long long)TOK * 1024, scale);
        gemm_bf_k<<<dim3(8, 16), 256, 0, stream>>>(
            ao_bf, 1024, w_out1_bf, b_out1, ybuf_bf, nullptr, 1024, 1024, 0);
        gemm_bf_k<<<dim3(8, 16), 256, 0, stream>>>(
            ybuf_bf, 1024, w_lin_bf, b_lin, Xchunk, nullptr, 1024, 1024, 1);
        // Q for the whole chunk (rows 0..1023 of w_in2 are wq)
        gemm_bf_k<<<dim3(8, 16), 256, 0, stream>>>(
            Xchunk, 1024, w_in2_bf, b_in2, Qchunk, nullptr, 1024, 1024, 0);

        // ---- Phase 2: one cooperative launch per chunk ----
        if (c == 0) {
            hipMemcpyAsync(cum, Xchunk, WIN * sizeof(ushort_t),
                           hipMemcpyDeviceToDevice, stream);
        }
        int i0 = (c == 0) ? 1 : w0;
        int nsteps = (c == 0) ? CHUNK - 1 : CHUNK;
        const ushort_t* QchunkP = Qchunk;
        ushort_t *cumP = cum, *KVbP = KVb, *AO2P = AO2;
        const ushort_t *win2P = w_in2_bf, *wout2P = w_out2_bf;
        const float *bin2P = b_in2, *bout2P = b_out2;
        float* outP = out;
        unsigned* barP = bar;
        unsigned eb = epoch_base;
        void* args[] = {&QchunkP, &i0, &w0, &nsteps, &cumP, &KVbP, &AO2P,
                        &win2P, &bin2P, &wout2P, &bout2P, &outP, &barP, &eb};
        hipLaunchCooperativeKernel((void*)scan_coop_k, dim3(NWG), dim3(256),
                                   args, 0, stream);
        epoch_base += 3u * (unsigned)nsteps;
    }
}

// Round 6
// 24543.756 us; speedup vs baseline: 1.7624x; 1.6739x over previous
//
#include <hip/hip_runtime.h>
#include <math.h>

// Problem constants
#define D_MODEL 1024
#define N_WIN   240
#define TOK     256
#define NH      16
#define DH      64
#define CHUNK   8
#define NCHUNK  30
#define WIN     ((size_t)TOK * D_MODEL)

typedef unsigned short ushort_t;
typedef __attribute__((ext_vector_type(8))) short short8;
typedef __attribute__((ext_vector_type(4))) float floatx4;

__device__ __forceinline__ float blo(unsigned u) { return __uint_as_float(u << 16); }
__device__ __forceinline__ float bhi(unsigned u) { return __uint_as_float(u & 0xffff0000u); }
__device__ __forceinline__ ushort_t f2bf(float f) {   // RNE
    unsigned u = __float_as_uint(f);
    unsigned lsb = (u >> 16) & 1u;
    u += 0x7fffu + lsb;
    return (ushort_t)(u >> 16);
}

// async global->LDS, 16B per lane
#define GLDS(g, l) __builtin_amdgcn_global_load_lds( \
    (const __attribute__((address_space(1))) unsigned int*)(g), \
    (__attribute__((address_space(3))) unsigned int*)(l), 16, 0, 0)

// ---------------------------------------------------------------------------
// Tree barrier primitives. Each barrier block = 320 unsigneds:
//   [g*32] 8 sub-counters, [256] root, [288] release. Monotonic epochs.
// Pollers spin on the release line only (no contention with arrivals).
// ---------------------------------------------------------------------------
__device__ __forceinline__ void bar_signal(unsigned* base, int g,
                                           unsigned subT, unsigned rootT,
                                           unsigned s)
{
    __threadfence();   // release: publish this WG's writes
    unsigned old = __hip_atomic_fetch_add(base + g * 32, 1u, __ATOMIC_RELAXED,
                                          __HIP_MEMORY_SCOPE_AGENT);
    if (old == subT - 1u) {
        unsigned r = __hip_atomic_fetch_add(base + 256, 1u, __ATOMIC_RELAXED,
                                            __HIP_MEMORY_SCOPE_AGENT);
        if (r == rootT - 1u)
            __hip_atomic_store(base + 288, s, __ATOMIC_RELAXED,
                               __HIP_MEMORY_SCOPE_AGENT);
    }
}
__device__ __forceinline__ void bar_wait(unsigned* base, unsigned s)
{
    while (__hip_atomic_load(base + 288, __ATOMIC_RELAXED,
                             __HIP_MEMORY_SCOPE_AGENT) < s)
        __builtin_amdgcn_s_sleep(1);
    __threadfence();   // acquire: drop stale cached lines
}

// ---------------------------------------------------------------------------
// fp32 -> bf16 cast
// ---------------------------------------------------------------------------
__global__ __launch_bounds__(256) void cast_bf_k(
    const float* __restrict__ s, ushort_t* __restrict__ d, int n)
{
    int i = (blockIdx.x * 256 + threadIdx.x) * 4;
    if (i >= n) return;
    float4 v = *(const float4*)(s + i);
    ushort4 o;
    o.x = f2bf(v.x); o.y = f2bf(v.y); o.z = f2bf(v.z); o.w = f2bf(v.w);
    *(ushort4*)(d + i) = o;
}

// ---------------------------------------------------------------------------
// Phase-1 bf16 MFMA GEMM core (m97 structure), 128x128 tile, BK=32.
// ---------------------------------------------------------------------------
template<bool GATHER>
__device__ __forceinline__ void gemm_core(
    const ushort_t* __restrict__ A, int lda, int w0,
    const ushort_t* __restrict__ W, const float* __restrict__ bias,
    ushort_t* __restrict__ Cb, float* __restrict__ Cf, int ldc,
    int K, int m0, int n0, int co, int relu)
{
    __shared__ ushort_t As[128 * 32];
    __shared__ ushort_t Bs[128 * 32];
    const int tid = threadIdx.x;
    const int wave = tid >> 6, lane = tid & 63;
    const int wm = wave & 1, wn = wave >> 1;

    int r0 = m0 + (tid >> 2), r1 = r0 + 64;
    if (GATHER) {
        r0 = (w0 + (r0 >> 8)) * 16 + (r0 & 255);
        r1 = (w0 + (r1 >> 8)) * 16 + (r1 & 255);
    }
    const int kcol = (tid & 3) * 8;
    const ushort_t* gA0 = A + (size_t)r0 * lda + kcol;
    const ushort_t* gA1 = A + (size_t)r1 * lda + kcol;
    const ushort_t* pW  = W + (size_t)n0 * K;
    const ushort_t* gB0 = pW + (size_t)(tid >> 2) * K + kcol;
    const ushort_t* gB1 = gB0 + (size_t)64 * K;
    ushort_t* lA = As + wave * 512;
    ushort_t* lB = Bs + wave * 512;

    floatx4 acc[4][4];
#pragma unroll
    for (int i = 0; i < 4; ++i)
#pragma unroll
        for (int j = 0; j < 4; ++j) acc[i][j] = (floatx4){0.f, 0.f, 0.f, 0.f};

    const int fr = lane & 15, fk = (lane >> 4) * 8;
    const int arow = (wm * 64 + fr) * 32 + fk;
    const int brow = (wn * 64 + fr) * 32 + fk;

    for (int k0 = 0; k0 < K; k0 += 32) {
        GLDS(gA0 + k0, lA);
        GLDS(gA1 + k0, lA + 2048);
        GLDS(gB0 + k0, lB);
        GLDS(gB1 + k0, lB + 2048);
        __syncthreads();
        short8 a[4], b[4];
#pragma unroll
        for (int mi = 0; mi < 4; ++mi) a[mi] = *(const short8*)&As[arow + mi * 512];
#pragma unroll
        for (int ni = 0; ni < 4; ++ni) b[ni] = *(const short8*)&Bs[brow + ni * 512];
#pragma unroll
        for (int mi = 0; mi < 4; ++mi)
#pragma unroll
            for (int ni = 0; ni < 4; ++ni)
                acc[mi][ni] = __builtin_amdgcn_mfma_f32_16x16x32_bf16(
                    a[mi], b[ni], acc[mi][ni], 0, 0, 0);
        __syncthreads();
    }

    const int crq = (lane >> 4) * 4;
    const int ccol = lane & 15;
#pragma unroll
    for (int mi = 0; mi < 4; ++mi) {
#pragma unroll
        for (int ni = 0; ni < 4; ++ni) {
            int lc = wn * 64 + ni * 16 + ccol;
            float bz = bias[n0 + lc];
#pragma unroll
            for (int rg = 0; rg < 4; ++rg) {
                int row = m0 + wm * 64 + mi * 16 + crq + rg;
                float v = acc[mi][ni][rg] + bz;
                if (relu) v = fmaxf(v, 0.f);
                size_t off = (size_t)row * ldc + co + lc;
                if (Cb) Cb[off] = f2bf(v);
                if (Cf) Cf[off] = v;
            }
        }
    }
}

__global__ __launch_bounds__(256) void gemm_bf_k(
    const ushort_t* __restrict__ A, int lda,
    const ushort_t* __restrict__ W, const float* __restrict__ bias,
    ushort_t* __restrict__ Cb, float* __restrict__ Cf, int ldc,
    int K, int relu)
{
    gemm_core<false>(A, lda, 0, W, bias, Cb, Cf, ldc, K,
                     blockIdx.y * 128, blockIdx.x * 128, blockIdx.x * 128, relu);
}

__global__ __launch_bounds__(256) void gemm_qkv_k(
    const ushort_t* __restrict__ path_bf, const ushort_t* __restrict__ W,
    const float* __restrict__ bias, ushort_t* __restrict__ Cb, int w0)
{
    gemm_core<true>(path_bf, 1024, w0, W, bias, Cb, nullptr, 3072, 1024,
                    blockIdx.y * 128, blockIdx.x * 128, blockIdx.x * 128, 0);
}

// ---------------------------------------------------------------------------
// Shared MFMA attention core: one (head, 64-row slice) per call.
// Block 256 = 4 waves; wave handles 16 rows. S=QK^T (MFMA), softmax in regs
// (16-lane shuffle), P via LDS (C-layout -> A-layout), V^T staged in halves,
// PV (MFMA). scale = 0.125 fixed.
// ---------------------------------------------------------------------------
#define PLD 260
#define VLD 132

struct ScanShared {
    ushort_t P[64 * PLD];
    ushort_t VT[64 * VLD];
    float    l[64];
};

__device__ __forceinline__ void attn_core(
    int h, int rs, int tid,
    const ushort_t* __restrict__ Q, int ldq,
    const ushort_t* __restrict__ K, const ushort_t* __restrict__ V, int ldkv,
    ushort_t* __restrict__ O, int ldo, ScanShared& sh)
{
    const int wave = tid >> 6, lane = tid & 63;
    const int fr = lane & 15, q = lane >> 4, fk = q * 8;
    const ushort_t* Qh = Q + (size_t)(rs * 64) * ldq + h * 64;
    const ushort_t* Kh = K + h * 64;
    const ushort_t* Vh = V + h * 64;
    const int m0 = wave * 16;

    floatx4 s[16];
#pragma unroll
    for (int nt = 0; nt < 16; ++nt) s[nt] = (floatx4){0.f, 0.f, 0.f, 0.f};
#pragma unroll
    for (int kc = 0; kc < 64; kc += 32) {
        short8 a = *(const short8*)(Qh + (size_t)(m0 + fr) * ldq + kc + fk);
#pragma unroll
        for (int nt = 0; nt < 16; ++nt) {
            short8 b = *(const short8*)(Kh + (size_t)(nt * 16 + fr) * ldkv + kc + fk);
            s[nt] = __builtin_amdgcn_mfma_f32_16x16x32_bf16(a, b, s[nt], 0, 0, 0);
        }
    }

    float rmax[4] = {-INFINITY, -INFINITY, -INFINITY, -INFINITY};
#pragma unroll
    for (int nt = 0; nt < 16; ++nt)
#pragma unroll
        for (int rg = 0; rg < 4; ++rg) rmax[rg] = fmaxf(rmax[rg], s[nt][rg]);
#pragma unroll
    for (int d = 1; d < 16; d <<= 1)
#pragma unroll
        for (int rg = 0; rg < 4; ++rg)
            rmax[rg] = fmaxf(rmax[rg], __shfl_xor(rmax[rg], d));

    float rsum[4] = {0.f, 0.f, 0.f, 0.f};
#pragma unroll
    for (int nt = 0; nt < 16; ++nt) {
#pragma unroll
        for (int rg = 0; rg < 4; ++rg) {
            float p = __expf((s[nt][rg] - rmax[rg]) * 0.125f);
            rsum[rg] += p;
            sh.P[(m0 + q * 4 + rg) * PLD + nt * 16 + fr] = f2bf(p);
        }
    }
#pragma unroll
    for (int d = 1; d < 16; d <<= 1)
#pragma unroll
        for (int rg = 0; rg < 4; ++rg) rsum[rg] += __shfl_xor(rsum[rg], d);
    if (fr == 0) {
#pragma unroll
        for (int rg = 0; rg < 4; ++rg) sh.l[m0 + q * 4 + rg] = rsum[rg];
    }
    __syncthreads();

    floatx4 o[4];
#pragma unroll
    for (int i = 0; i < 4; ++i) o[i] = (floatx4){0.f, 0.f, 0.f, 0.f};

#pragma unroll
    for (int half = 0; half < 2; ++half) {
        {
            int r = tid & 127, cp = tid >> 7;
            const ushort_t* vrow = Vh + (size_t)(half * 128 + r) * ldkv + cp * 32;
#pragma unroll
            for (int c = 0; c < 4; ++c) {
                uint4 pk = *(const uint4*)(vrow + c * 8);
                int d0 = cp * 32 + c * 8;
                sh.VT[(d0 + 0) * VLD + r] = (ushort_t)(pk.x & 0xffff);
                sh.VT[(d0 + 1) * VLD + r] = (ushort_t)(pk.x >> 16);
                sh.VT[(d0 + 2) * VLD + r] = (ushort_t)(pk.y & 0xffff);
                sh.VT[(d0 + 3) * VLD + r] = (ushort_t)(pk.y >> 16);
                sh.VT[(d0 + 4) * VLD + r] = (ushort_t)(pk.z & 0xffff);
                sh.VT[(d0 + 5) * VLD + r] = (ushort_t)(pk.z >> 16);
                sh.VT[(d0 + 6) * VLD + r] = (ushort_t)(pk.w & 0xffff);
                sh.VT[(d0 + 7) * VLD + r] = (ushort_t)(pk.w >> 16);
            }
        }
        __syncthreads();
#pragma unroll
        for (int ks = 0; ks < 4; ++ks) {
            short8 a = *(const short8*)&sh.P[(m0 + fr) * PLD + half * 128 + ks * 32 + fk];
#pragma unroll
            for (int nt2 = 0; nt2 < 4; ++nt2) {
                short8 b = *(const short8*)&sh.VT[(nt2 * 16 + fr) * VLD + ks * 32 + fk];
                o[nt2] = __builtin_amdgcn_mfma_f32_16x16x32_bf16(a, b, o[nt2], 0, 0, 0);
            }
        }
        __syncthreads();
    }

    float linv[4];
#pragma unroll
    for (int rg = 0; rg < 4; ++rg) linv[rg] = 1.f / sh.l[m0 + q * 4 + rg];
#pragma unroll
    for (int nt2 = 0; nt2 < 4; ++nt2)
#pragma unroll
        for (int rg = 0; rg < 4; ++rg) {
            int row = rs * 64 + m0 + q * 4 + rg;
            O[(size_t)row * ldo + h * 64 + nt2 * 16 + fr] =
                f2bf(o[nt2][rg] * linv[rg]);
        }
}

// Phase-1 standalone MFMA attention: grid (4 row-slices, NH, batch)
__global__ __launch_bounds__(256) void attn_mfma_k(
    const ushort_t* __restrict__ qkv, ushort_t* __restrict__ ao)
{
    __shared__ ScanShared sh;
    const int rs = blockIdx.x, h = blockIdx.y, b = blockIdx.z;
    const ushort_t* base = qkv + (size_t)b * TOK * 3072;
    attn_core(h, rs, threadIdx.x, base, 3072, base + 1024, base + 2048, 3072,
              ao + (size_t)b * TOK * 1024, 1024, sh);
}

// ---------------------------------------------------------------------------
// Register-weight tall-skinny GEMM: C[256 x 16] = A[256 x 1024] @ Wreg^T + bz
// wreg: 32 b-frags held in VGPRs (loaded once per launch).
// ---------------------------------------------------------------------------
__device__ __forceinline__ void ts_gemm_reg(
    const ushort_t* __restrict__ A, const short8* wreg, float bz,
    ushort_t* __restrict__ Cb, float* __restrict__ Cf, int ldc, int cc,
    int wave, int lane)
{
    const int fr = lane & 15, fk = (lane >> 4) * 8, q = lane >> 4;
    const int m0v = wave * 64;
    floatx4 acc[4];
#pragma unroll
    for (int i = 0; i < 4; ++i) acc[i] = (floatx4){0.f, 0.f, 0.f, 0.f};
    const ushort_t* aptr = A + (size_t)(m0v + fr) * 1024 + fk;
#pragma unroll
    for (int k = 0; k < 32; ++k) {
#pragma unroll
        for (int mi = 0; mi < 4; ++mi) {
            short8 a = *(const short8*)(aptr + (size_t)(mi * 16) * 1024 + k * 32);
            acc[mi] = __builtin_amdgcn_mfma_f32_16x16x32_bf16(a, wreg[k], acc[mi], 0, 0, 0);
        }
    }
#pragma unroll
    for (int mi = 0; mi < 4; ++mi) {
#pragma unroll
        for (int rg = 0; rg < 4; ++rg) {
            int row = m0v + mi * 16 + q * 4 + rg;
            float v = acc[mi][rg] + bz;
            size_t off = (size_t)row * ldc + cc + fr;
            Cb[off] = f2bf(v);
            if (Cf) Cf[off] = v;
        }
    }
}

// ===========================================================================
// Cooperative phase-2 kernel. Grid 192 WGs x 256 thr (1 block/CU).
//  Role A (WGs 64..191): KV projection, weights in 128 VGPRs.
//  Role B+C (WGs 0..63): MFMA attention + out projection (weights in VGPRs).
// Barriers: barA (KV ready, 8 subs x 16), barB (attn done, 4 x 16),
//           barC (cum ready, 4 x 16). Monotonic step index s across launches.
// ===========================================================================
__global__ __launch_bounds__(256, 1) void scan_coop_k(
    const ushort_t* __restrict__ Qchunk, int i0, int w0, int nsteps,
    ushort_t* __restrict__ cum, ushort_t* __restrict__ KVb,
    ushort_t* __restrict__ AO2,
    const ushort_t* __restrict__ w_in2, const float* __restrict__ b_in2,
    const ushort_t* __restrict__ w_out2, const float* __restrict__ b_out2,
    float* __restrict__ outp, unsigned* __restrict__ bar, unsigned s0)
{
    __shared__ ScanShared sh;
    const int wg = blockIdx.x, tid = threadIdx.x;
    const int wave = tid >> 6, lane = tid & 63;
    const int fr = lane & 15, fk = (lane >> 4) * 8;
    unsigned* barA = bar;
    unsigned* barB = bar + 320;
    unsigned* barC = bar + 640;

    if (wg >= 64) {
        // ---------------- role A: KV = cum @ wkv^T ----------------
        const int n0 = (wg - 64) * 16;
        const int g = (wg - 64) & 7;
        short8 wreg[32];
        const ushort_t* Wn = w_in2 + (size_t)(1024 + n0 + fr) * 1024 + fk;
#pragma unroll
        for (int k = 0; k < 32; ++k) wreg[k] = *(const short8*)(Wn + k * 32);
        const float bz = b_in2[1024 + n0 + fr];

        unsigned s = s0;
        for (int t = 0; t < nsteps; ++t, ++s) {
            ts_gemm_reg(cum, wreg, bz, KVb, nullptr, 2048, n0, wave, lane);
            __syncthreads();
            if (tid == 0) {
                bar_signal(barA, g, 16u * s, 8u * s, s);   // publish KVb
                bar_wait(barC, s);                         // wait for cum_t
            }
            __syncthreads();
        }
    } else {
        // ---------------- role B+C ----------------
        const int h = wg >> 2, rs = wg & 3;     // stage B assignment
        const int n0 = wg * 16;                 // stage C columns
        const int g = wg & 3;
        short8 wreg[32];
        const ushort_t* Wn = w_out2 + (size_t)(n0 + fr) * 1024 + fk;
#pragma unroll
        for (int k = 0; k < 32; ++k) wreg[k] = *(const short8*)(Wn + k * 32);
        const float bz = b_out2[n0 + fr];

        unsigned s = s0;
        for (int t = 0; t < nsteps; ++t, ++s) {
            const int i = i0 + t;
            if (tid == 0) bar_wait(barA, s);    // KVb ready
            __syncthreads();
            attn_core(h, rs, tid, Qchunk + (size_t)(i - w0) * WIN, 1024,
                      KVb, KVb + 1024, 2048, AO2, 1024, sh);
            __syncthreads();
            if (tid == 0) {
                bar_signal(barB, g, 16u * s, 4u * s, s);   // AO2 published
                bar_wait(barB, s);
            }
            __syncthreads();
            float* Cf = (i == N_WIN - 1) ? outp : nullptr;
            ts_gemm_reg(AO2, wreg, bz, cum, Cf, 1024, n0, wave, lane);
            __syncthreads();
            if (tid == 0) bar_signal(barC, g, 16u * s, 4u * s, s);  // cum ready
            __syncthreads();
        }
    }
}

// ---------------------------------------------------------------------------
extern "C" void kernel_launch(void* const* d_in, const int* in_sizes, int n_in,
                              void* d_out, int out_size, void* d_ws, size_t ws_size,
                              hipStream_t stream)
{
    const float* path   = (const float*)d_in[0];
    const float* w_in1  = (const float*)d_in[1];
    const float* b_in1  = (const float*)d_in[2];
    const float* w_out1 = (const float*)d_in[3];
    const float* b_out1 = (const float*)d_in[4];
    const float* w_lin  = (const float*)d_in[5];
    const float* b_lin  = (const float*)d_in[6];
    const float* w_in2  = (const float*)d_in[7];
    const float* b_in2  = (const float*)d_in[8];
    const float* w_out2 = (const float*)d_in[9];
    const float* b_out2 = (const float*)d_in[10];
    float* out = (float*)d_out;

    // workspace: barriers (4 KB) then bf16 buffers (~55 MB)
    unsigned* bar = (unsigned*)d_ws;
    ushort_t* ws = (ushort_t*)d_ws + 2048;
    ushort_t* path_bf  = ws;                              // 4096*1024
    ushort_t* w_in1_bf = path_bf  + (size_t)4096 * 1024;  // 3072*1024
    ushort_t* w_out1_bf= w_in1_bf + (size_t)3072 * 1024;
    ushort_t* w_lin_bf = w_out1_bf+ (size_t)1024 * 1024;
    ushort_t* w_in2_bf = w_lin_bf + (size_t)1024 * 1024;  // 3072*1024
    ushort_t* w_out2_bf= w_in2_bf + (size_t)3072 * 1024;
    ushort_t* qkv_bf   = w_out2_bf+ (size_t)1024 * 1024;  // 2048*3072
    ushort_t* ybuf_bf  = qkv_bf;                          // alias (qkv dead)
    ushort_t* ao_bf    = qkv_bf   + (size_t)2048 * 3072;  // 2048*1024
    ushort_t* Xchunk   = ao_bf    + (size_t)2048 * 1024;  // 2048*1024
    ushort_t* Qchunk   = Xchunk   + (size_t)2048 * 1024;  // 2048*1024
    ushort_t* KVb      = Qchunk   + (size_t)2048 * 1024;  // 256*2048
    ushort_t* AO2      = KVb + 2 * WIN;                   // 256*1024
    ushort_t* cum      = AO2 + WIN;                       // 256*1024

    hipMemsetAsync(bar, 0, 8192, stream);

    cast_bf_k<<<4096, 256, 0, stream>>>(path,  path_bf,  4096 * 1024);
    cast_bf_k<<<3072, 256, 0, stream>>>(w_in1, w_in1_bf, 3072 * 1024);
    cast_bf_k<<<1024, 256, 0, stream>>>(w_out1, w_out1_bf, 1024 * 1024);
    cast_bf_k<<<1024, 256, 0, stream>>>(w_lin, w_lin_bf, 1024 * 1024);
    cast_bf_k<<<3072, 256, 0, stream>>>(w_in2, w_in2_bf, 3072 * 1024);
    cast_bf_k<<<1024, 256, 0, stream>>>(w_out2, w_out2_bf, 1024 * 1024);

    unsigned sbase = 1;
    for (int c = 0; c < NCHUNK; ++c) {
        int w0 = c * CHUNK;
        // ---- Phase 1 for windows [w0, w0+CHUNK) ----
        gemm_qkv_k<<<dim3(24, 16), 256, 0, stream>>>(
            path_bf, w_in1_bf, b_in1, qkv_bf, w0);
        attn_mfma_k<<<dim3(4, NH, CHUNK), 256, 0, stream>>>(qkv_bf, ao_bf);
        gemm_bf_k<<<dim3(8, 16), 256, 0, stream>>>(
            ao_bf, 1024, w_out1_bf, b_out1, ybuf_bf, nullptr, 1024, 1024, 0);
        gemm_bf_k<<<dim3(8, 16), 256, 0, stream>>>(
            ybuf_bf, 1024, w_lin_bf, b_lin, Xchunk, nullptr, 1024, 1024, 1);
        // Q for the whole chunk (rows 0..1023 of w_in2 are wq)
        gemm_bf_k<<<dim3(8, 16), 256, 0, stream>>>(
            Xchunk, 1024, w_in2_bf, b_in2, Qchunk, nullptr, 1024, 1024, 0);

        // ---- Phase 2: one cooperative launch per chunk ----
        if (c == 0) {
            hipMemcpyAsync(cum, Xchunk, WIN * sizeof(ushort_t),
                           hipMemcpyDeviceToDevice, stream);
        }
        int i0 = (c == 0) ? 1 : w0;
        int nsteps = (c == 0) ? CHUNK - 1 : CHUNK;
        const ushort_t* QchunkP = Qchunk;
        ushort_t *cumP = cum, *KVbP = KVb, *AO2P = AO2;
        const ushort_t *win2P = w_in2_bf, *wout2P = w_out2_bf;
        const float *bin2P = b_in2, *bout2P = b_out2;
        float* outP = out;
        unsigned* barP = bar;
        unsigned sb = sbase;
        void* args[] = {&QchunkP, &i0, &w0, &nsteps, &cumP, &KVbP, &AO2P,
                        &win2P, &bin2P, &wout2P, &bout2P, &outP, &barP, &sb};
        hipLaunchCooperativeKernel((void*)scan_coop_k, dim3(192), dim3(256),
                                   args, 0, stream);
        sbase += (unsigned)nsteps;
    }
}